// Round 2
// baseline (629.169 us; speedup 1.0000x reference)
//
#include <hip/hip_runtime.h>
#include <hip/hip_bf16.h>
#include <cstdint>

#define BSZ 4
#define NN 256
#define DXC 256
#define DFFC 1024
#define ROWS (BSZ*NN)   // 1024

// ---------------------------------------------------------------------------
// Generic small GEMM (all fp32): C[M,Nn] = epi(A[M,K] @ B[K,Nn] + bias)
// BM=BN=BK=32, 256 threads, 2x2 outputs/thread.
// EPI: 0 = +bias; 1 = (+bias)*mask[row]; 2 = relu(+bias)
// blockIdx.z selects (B,bias,C) pointer triple (fuses Q/K/V into one launch).
// ---------------------------------------------------------------------------
template <int EPI>
__global__ __launch_bounds__(256) void gemm32(
    const float* __restrict__ A,
    const float* __restrict__ B0, const float* __restrict__ B1,
    const float* __restrict__ B2,
    const float* __restrict__ bias0, const float* __restrict__ bias1,
    const float* __restrict__ bias2,
    float* __restrict__ C0, float* __restrict__ C1, float* __restrict__ C2,
    const float* __restrict__ mask,
    int M, int Nn, int K)
{
    const float* B = B0; const float* bias = bias0; float* C = C0;
    if (blockIdx.z == 1) { B = B1; bias = bias1; C = C1; }
    if (blockIdx.z == 2) { B = B2; bias = bias2; C = C2; }

    __shared__ float As[32][36];   // +4 pad: float4-aligned rows, no bank conflicts
    __shared__ float Bs[32][36];

    const int tid  = threadIdx.x;
    const int row0 = blockIdx.y * 32;
    const int col0 = blockIdx.x * 32;
    const int tx = tid & 15, ty = tid >> 4;

    const int la_r = tid >> 3;        // 0..31
    const int la_k = (tid & 7) * 4;   // 0,4,...,28

    float acc00 = 0.f, acc01 = 0.f, acc10 = 0.f, acc11 = 0.f;

    for (int k0 = 0; k0 < K; k0 += 32) {
        *(float4*)&As[la_r][la_k] = *(const float4*)(A + (size_t)(row0 + la_r) * K + (k0 + la_k));
        *(float4*)&Bs[la_r][la_k] = *(const float4*)(B + (size_t)(k0 + la_r) * Nn + (col0 + la_k));
        __syncthreads();
        #pragma unroll
        for (int k = 0; k < 32; ++k) {
            float a0v = As[2*ty][k],   a1v = As[2*ty+1][k];
            float b0v = Bs[k][2*tx],   b1v = Bs[k][2*tx+1];
            acc00 += a0v * b0v; acc01 += a0v * b1v;
            acc10 += a1v * b0v; acc11 += a1v * b1v;
        }
        __syncthreads();
    }

    const int r0 = row0 + 2*ty, c0 = col0 + 2*tx;
    const float bi0 = bias[c0], bi1 = bias[c0 + 1];
    float v00 = acc00 + bi0, v01 = acc01 + bi1;
    float v10 = acc10 + bi0, v11 = acc11 + bi1;
    if constexpr (EPI == 1) {
        float m0 = mask[r0], m1 = mask[r0 + 1];
        v00 *= m0; v01 *= m0; v10 *= m1; v11 *= m1;
    } else if constexpr (EPI == 2) {
        v00 = fmaxf(v00, 0.f); v01 = fmaxf(v01, 0.f);
        v10 = fmaxf(v10, 0.f); v11 = fmaxf(v11, 0.f);
    }
    C[(size_t)r0 * Nn + c0]       = v00; C[(size_t)r0 * Nn + c0 + 1]       = v01;
    C[(size_t)(r0+1) * Nn + c0]   = v10; C[(size_t)(r0+1) * Nn + c0 + 1]   = v11;
}

// ---------------------------------------------------------------------------
// Attention core: one block per (b,i). Streams e_add/e_mul once (HBM-bound).
// Y[j,hd] = (Q[i,hd]*K[j,hd]/sqrt(32))*(e_mul*ee + 1) + e_add*ee; mask -> -inf;
// softmax over j WITHOUT max subtraction (|y| <~ 35, exp fits fp32 easily);
// wV[hd] = sum_j p*V[j,hd] / sum_j p; out = y_x_add + (y_x_mul+1)*wV.
// Wave = j phase (wave-uniform j -> fully coalesced 1KB/tensor/wave-iter);
// lane owns channels 4*lane..4*lane+3.
// ---------------------------------------------------------------------------
__global__ __launch_bounds__(256) void attn_kernel(
    const float* __restrict__ Qb, const float* __restrict__ Kb, const float* __restrict__ Vb,
    const float* __restrict__ e_add, const float* __restrict__ e_mul,
    const float* __restrict__ y_x_add, const float* __restrict__ y_x_mul,
    const float* __restrict__ nmask,
    float* __restrict__ nXi)
{
    const int row  = blockIdx.x;       // b*N + i
    const int b    = row >> 8;
    const int tid  = threadIdx.x;
    const int wv   = tid >> 6;         // j phase 0..3
    const int lane = tid & 63;
    const int hd   = lane << 2;

    const float mi = nmask[row];
    float4 q = *(const float4*)(Qb + (size_t)row * DXC + hd);
    const float inv = 0.17677669529663687f;  // 1/sqrt(32)
    q.x *= inv; q.y *= inv; q.z *= inv; q.w *= inv;

    const float* ea_p = e_add + (size_t)row * NN * DXC + hd;
    const float* em_p = e_mul + (size_t)row * NN * DXC + hd;
    const float* kp = Kb + (size_t)(b << 8) * DXC + hd;
    const float* vp = Vb + (size_t)(b << 8) * DXC + hd;
    const float* mp = nmask + (b << 8);

    float l0=0.f,l1=0.f,l2=0.f,l3=0.f;
    float a0=0.f,a1=0.f,a2=0.f,a3=0.f;

    #pragma unroll 4
    for (int j = wv; j < NN; j += 4) {
        const float mj = mp[j];                 // wave-uniform
        const float ee = mi * mj;
        const float4 k4 = *(const float4*)(kp + (size_t)j * DXC);
        const float4 v4 = *(const float4*)(vp + (size_t)j * DXC);
        const float4 em = *(const float4*)(em_p + (size_t)j * DXC);
        const float4 ea = *(const float4*)(ea_p + (size_t)j * DXC);
        float y0 = (q.x*k4.x) * (em.x*ee + 1.f) + ea.x*ee;
        float y1 = (q.y*k4.y) * (em.y*ee + 1.f) + ea.y*ee;
        float y2 = (q.z*k4.z) * (em.z*ee + 1.f) + ea.z*ee;
        float y3 = (q.w*k4.w) * (em.w*ee + 1.f) + ea.w*ee;
        if (!(mj > 0.f)) { y0 = y1 = y2 = y3 = -1e30f; }  // exp -> 0
        const float p0 = __expf(y0), p1 = __expf(y1), p2 = __expf(y2), p3 = __expf(y3);
        l0 += p0; l1 += p1; l2 += p2; l3 += p3;
        a0 += p0*v4.x; a1 += p1*v4.y; a2 += p2*v4.z; a3 += p3*v4.w;
    }

    __shared__ float sl[4][256];
    __shared__ float sa[4][256];
    *(float4*)&sl[wv][hd] = make_float4(l0, l1, l2, l3);
    *(float4*)&sa[wv][hd] = make_float4(a0, a1, a2, a3);
    __syncthreads();

    const int c = tid;  // channel 0..255
    const float L = sl[0][c] + sl[1][c] + sl[2][c] + sl[3][c];
    const float A = sa[0][c] + sa[1][c] + sa[2][c] + sa[3][c];
    const float wV = A / L;
    const float yxa = y_x_add[b * DXC + c];
    const float yxm = y_x_mul[b * DXC + c];
    nXi[(size_t)row * DXC + c] = yxa + (yxm + 1.f) * wV;
}

// ---------------------------------------------------------------------------
// LayerNorm: one block per row, 256 threads = 256 channels.
// out = (s - mean(s)) * rsqrt(var(s)+eps) * g + beta,  s = base + delta
// ---------------------------------------------------------------------------
__global__ __launch_bounds__(256) void ln_kernel(
    const float* __restrict__ base, const float* __restrict__ delta,
    const float* __restrict__ g, const float* __restrict__ be,
    float* __restrict__ out)
{
    const int row = blockIdx.x, t = threadIdx.x;
    const size_t idx = (size_t)row * DXC + t;
    const float s = base[idx] + delta[idx];
    __shared__ float red[8];
    float sum = s, sq = s * s;
    #pragma unroll
    for (int o = 32; o > 0; o >>= 1) { sum += __shfl_down(sum, o); sq += __shfl_down(sq, o); }
    if ((t & 63) == 0) { red[t >> 6] = sum; red[4 + (t >> 6)] = sq; }
    __syncthreads();
    sum = red[0] + red[1] + red[2] + red[3];
    sq  = red[4] + red[5] + red[6] + red[7];
    const float mean = sum * (1.f / DXC);
    const float var  = sq * (1.f / DXC) - mean * mean;
    const float r = rsqrtf(var + 1e-5f);
    out[idx] = (s - mean) * r * g[t] + be[t];
}

// ---------------------------------------------------------------------------
extern "C" void kernel_launch(void* const* d_in, const int* in_sizes, int n_in,
                              void* d_out, int out_size, void* d_ws, size_t ws_size,
                              hipStream_t stream)
{
    const float* X       = (const float*)d_in[0];
    const float* e_add   = (const float*)d_in[1];
    const float* e_mul   = (const float*)d_in[2];
    const float* y_x_add = (const float*)d_in[3];
    const float* y_x_mul = (const float*)d_in[4];
    const float* nmask   = (const float*)d_in[5];
    const float* Wq = (const float*)d_in[6];
    const float* bq = (const float*)d_in[7];
    const float* Wk = (const float*)d_in[8];
    const float* bk = (const float*)d_in[9];
    const float* Wv = (const float*)d_in[10];
    const float* bv = (const float*)d_in[11];
    const float* Wo = (const float*)d_in[12];
    const float* bo = (const float*)d_in[13];
    const float* W1 = (const float*)d_in[14];
    const float* b1 = (const float*)d_in[15];
    const float* W2 = (const float*)d_in[16];
    const float* b2 = (const float*)d_in[17];
    const float* g1 = (const float*)d_in[18];
    const float* be1= (const float*)d_in[19];
    const float* g2 = (const float*)d_in[20];
    const float* be2= (const float*)d_in[21];

    float* ws  = (float*)d_ws;
    float* Qb  = ws + 0 * 262144;
    float* Kb  = ws + 1 * 262144;
    float* Vb  = ws + 2 * 262144;
    float* nXi = ws + 3 * 262144;   // y_x_add + (y_x_mul+1)*weighted_V
    float* nXo = ws + 4 * 262144;   // (nXi @ Wo + bo) * mask
    float* X1b = ws + 5 * 262144;   // LN1 output
    float* ffo = ws + 6 * 262144;   // relu(X1@W1+b1)@W2 + b2
    float* hb  = ws + 7 * 262144;   // 1024x1024 hidden

    // Q,K,V = (X @ W + b) * mask  (one launch, z selects q/k/v)
    gemm32<1><<<dim3(DXC/32, ROWS/32, 3), 256, 0, stream>>>(
        X, Wq, Wk, Wv, bq, bk, bv, Qb, Kb, Vb, nmask, ROWS, DXC, DXC);

    // attention core (HBM-bound over e_add/e_mul)
    attn_kernel<<<dim3(ROWS), 256, 0, stream>>>(
        Qb, Kb, Vb, e_add, e_mul, y_x_add, y_x_mul, nmask, nXi);

    // newX = (nXi @ Wo + bo) * mask
    gemm32<1><<<dim3(DXC/32, ROWS/32, 1), 256, 0, stream>>>(
        nXi, Wo, Wo, Wo, bo, bo, bo, nXo, nXo, nXo, nmask, ROWS, DXC, DXC);

    // X1 = LN(X + newX)
    ln_kernel<<<dim3(ROWS), 256, 0, stream>>>(X, nXo, g1, be1, X1b);

    // h = relu(X1 @ W1 + b1)
    gemm32<2><<<dim3(DFFC/32, ROWS/32, 1), 256, 0, stream>>>(
        X1b, W1, W1, W1, b1, b1, b1, hb, hb, hb, nullptr, ROWS, DFFC, DXC);

    // ffo = h @ W2 + b2
    gemm32<0><<<dim3(DXC/32, ROWS/32, 1), 256, 0, stream>>>(
        hb, W2, W2, W2, b2, b2, b2, ffo, ffo, ffo, nullptr, ROWS, DXC, DFFC);

    // out = LN(X1 + ffo)
    ln_kernel<<<dim3(ROWS), 256, 0, stream>>>(X1b, ffo, g2, be2, (float*)d_out);
}